// Round 13
// baseline (815.384 us; speedup 1.0000x reference)
//
#include <hip/hip_runtime.h>
#include <hip/hip_bf16.h>
#include <cmath>

#define NN 49920
#define EE 200000
#define BB 128

typedef __attribute__((ext_vector_type(8))) short short8;
typedef __attribute__((ext_vector_type(4))) float floatx4;
typedef __attribute__((ext_vector_type(2))) float float2v;

union u8x16 { short8 v; unsigned short u[8]; };

__device__ __forceinline__ float bits2f(unsigned short u) {
    union { unsigned int i; float f; } c; c.i = ((unsigned int)u) << 16; return c.f;
}
__device__ __forceinline__ unsigned short f2bits(float f) {
    union { float f; unsigned int i; } c; c.f = f;
    unsigned int x = c.i;
    return (unsigned short)((x + 0x7fffu + ((x >> 16) & 1u)) >> 16);   // RNE
}
__device__ __forceinline__ unsigned short f2bits_trunc(float f) {
    union { float f; unsigned int i; } c; c.f = f;
    return (unsigned short)(c.i >> 16);                               // truncate (1 op)
}
__device__ __forceinline__ float2v cvt2(unsigned int w) {
    union { unsigned int i; float f; } lo, hi;
    lo.i = w << 16; hi.i = w & 0xffff0000u;
    return (float2v){lo.f, hi.f};
}
__device__ __forceinline__ float2v absv(float2v v) {
    union { float2v f; unsigned int u[2]; } c; c.f = v;
    c.u[0] &= 0x7fffffffu; c.u[1] &= 0x7fffffffu;
    return c.f;
}

typedef const __attribute__((address_space(1))) void* gvp;
typedef __attribute__((address_space(3))) void* lvp;
__device__ __forceinline__ void gll16(const void* g, void* l) {
    __builtin_amdgcn_global_load_lds((gvp)g, (lvp)l, 16, 0, 0);
}

// ---------------- small utility kernels ----------------
__global__ void zero_int_kernel(int* __restrict__ p, int n) {
    int i = blockIdx.x * blockDim.x + threadIdx.x;
    if (i < n) p[i] = 0;
}

__global__ void convert_bf16_kernel(const float* __restrict__ src, unsigned short* __restrict__ dst, int n) {
    int i = blockIdx.x * blockDim.x + threadIdx.x;
    if (i < n) dst[i] = f2bits(src[i]);
}

// fused conversion of ALL weights
__global__ void convert_weights_kernel(
    const float* __restrict__ Wl1, const float* __restrict__ Wr1,
    const float* __restrict__ Wl2, const float* __restrict__ Wr2,
    const float* __restrict__ We1, const float* __restrict__ We2,
    const float* __restrict__ bl2, const float* __restrict__ br2,
    unsigned short* __restrict__ wtl1, unsigned short* __restrict__ wtr1,
    unsigned short* __restrict__ wtlr2, unsigned short* __restrict__ weT1,
    unsigned short* __restrict__ weT2, float* __restrict__ blr2) {
    int b = blockIdx.x, tid = threadIdx.x;
    if (b < 1024) {                       // Wl1/Wr1 [128][1024] -> WT [1024][128]
        const float* W = (b < 512) ? Wl1 : Wr1;
        unsigned short* WT = (b < 512) ? wtl1 : wtr1;
        int i = ((b & 511) << 8) + tid;
        int n = i >> 7, k = i & 127;
        WT[i] = f2bits(W[k * 1024 + n]);
    } else if (b < 3072) {                // Wl2/Wr2 [1024][256] -> wtlr2 [512][1024]
        int bb = b - 1024;
        const float* W = (bb < 1024) ? Wl2 : Wr2;
        int i = ((bb & 1023) << 8) + tid;
        int n = i >> 10, k = i & 1023;
        int off = (bb < 1024) ? 0 : 262144;
        wtlr2[off + i] = f2bits(W[k * 256 + n]);
    } else if (b < 3136) {                // We1 [16][1024] -> weT1 [1024][16]
        int i = ((b - 3072) << 8) + tid;
        int col = i >> 4, k = i & 15;
        weT1[i] = f2bits(We1[k * 1024 + col]);
    } else if (b < 3152) {                // We2 [16][256] -> weT2 [256][16]
        int i = ((b - 3136) << 8) + tid;
        int col = i >> 4, k = i & 15;
        weT2[i] = f2bits(We2[k * 256 + col]);
    } else {                              // blr2 = bl2 | br2 (512 f32)
        int i = ((b - 3152) << 8) + tid;
        if (i < 512) blr2[i] = (i < 256) ? bl2[i] : br2[i - 256];
    }
}

// ---------------- bf16 MFMA GEMM (B^T input, async staging, split output) ----
__global__ __launch_bounds__(256) void mfma_gemm_bt_kernel(
    const unsigned short* __restrict__ A, const unsigned short* __restrict__ WT,
    const float* __restrict__ bias, const float* __restrict__ bias2,
    unsigned short* __restrict__ C, unsigned short* __restrict__ C2,
    int M, int K, int Nout) {
    __shared__ unsigned short As[128 * 32];
    __shared__ unsigned short Bs[128 * 32];
    int tid = threadIdx.x;
    int lane = tid & 63, wid = tid >> 6;
    int gm0 = blockIdx.y * 128, gn0 = blockIdx.x * 128;
    int wm = (wid & 1) * 64, wn = (wid >> 1) * 64;
    int l15 = lane & 15, quad = lane >> 4;
    int r0 = wid * 32;
    int gr = r0 + (lane >> 2);
    int kc = (lane & 3) * 8;

    floatx4 acc[4][4];
#pragma unroll
    for (int i = 0; i < 4; i++)
#pragma unroll
        for (int j = 0; j < 4; j++)
#pragma unroll
            for (int r = 0; r < 4; r++) acc[i][j][r] = 0.f;

    const unsigned short* Ap0 = &A[(size_t)(gm0 + gr) * K + kc];
    const unsigned short* Ap1 = Ap0 + (size_t)16 * K;
    const unsigned short* Bp0 = &WT[(size_t)(gn0 + gr) * K + kc];
    const unsigned short* Bp1 = Bp0 + (size_t)16 * K;
    unsigned short* as0 = &As[r0 * 32];
    unsigned short* as1 = &As[(r0 + 16) * 32];
    unsigned short* bs0 = &Bs[r0 * 32];
    unsigned short* bs1 = &Bs[(r0 + 16) * 32];

    for (int k0 = 0; k0 < K; k0 += 32) {
        __syncthreads();
        gll16(Ap0 + k0, as0);
        gll16(Ap1 + k0, as1);
        gll16(Bp0 + k0, bs0);
        gll16(Bp1 + k0, bs1);
        __syncthreads();
        short8 af[4], bfr[4];
#pragma unroll
        for (int i = 0; i < 4; i++)
            af[i] = *(const short8*)&As[(wm + 16 * i + l15) * 32 + quad * 8];
#pragma unroll
        for (int j = 0; j < 4; j++)
            bfr[j] = *(const short8*)&Bs[(wn + 16 * j + l15) * 32 + quad * 8];
#pragma unroll
        for (int i = 0; i < 4; i++)
#pragma unroll
            for (int j = 0; j < 4; j++)
                acc[i][j] = __builtin_amdgcn_mfma_f32_16x16x32_bf16(af[i], bfr[j], acc[i][j], 0, 0, 0);
    }

    unsigned short* Cw = C;
    const float* bp = bias;
    int colb = gn0 + wn + l15;
    if (gn0 >= Nout) { Cw = C2; bp = bias2; colb -= Nout; }
#pragma unroll
    for (int i = 0; i < 4; i++) {
#pragma unroll
        for (int j = 0; j < 4; j++) {
            int col = colb + 16 * j;
            float bv = bp[col];
#pragma unroll
            for (int r = 0; r < 4; r++) {
                int rrow = gm0 + wm + 16 * i + quad * 4 + r;
                Cw[(size_t)rrow * Nout + col] = f2bits(acc[i][j][r] + bv);
            }
        }
    }
}

// ---------------- CSR build ----------------
__global__ void hist_kernel(const int* __restrict__ ei, int* __restrict__ counts, int E) {
    int e = blockIdx.x * blockDim.x + threadIdx.x;
    if (e < E) atomicAdd(&counts[ei[E + e]], 1);
}

__global__ __launch_bounds__(1024) void scan_kernel(
    const int* __restrict__ counts, int* __restrict__ offsets,
    int* __restrict__ woff, int N) {
    __shared__ int partial[1024];
    int tid = threadIdx.x;
    const int CH = (N + 1023) >> 10;
    int b0 = tid * CH;
    int s = 0;
    for (int i = 0; i < CH; i++) { int idx = b0 + i; if (idx < N) s += counts[idx]; }
    partial[tid] = s;
    __syncthreads();
    if (tid == 0) {
        int acc = 0;
        for (int i = 0; i < 1024; i++) { int t = partial[i]; partial[i] = acc; acc += t; }
        offsets[N] = acc;
    }
    __syncthreads();
    int run = partial[tid];
    for (int i = 0; i < CH; i++) {
        int idx = b0 + i;
        if (idx < N) { offsets[idx] = run; woff[idx] = run; run += counts[idx]; }
    }
}

__global__ void scatter_kernel(const int* __restrict__ ei, int* __restrict__ woff,
                               int* __restrict__ perm, int* __restrict__ srcs,
                               int* __restrict__ dsts, int E) {
    int e = blockIdx.x * blockDim.x + threadIdx.x;
    if (e < E) {
        int d = ei[E + e];
        int slot = atomicAdd(&woff[d], 1);
        perm[slot] = e;
        srcs[slot] = ei[e];
        dsts[slot] = d;
    }
}

// ---------------- edge scoring v9: quarter-wave edges, short reduces ----------
template<int HC>
__global__ __launch_bounds__(256) void edge_score_v9_kernel(
    const unsigned short* __restrict__ xl, const unsigned short* __restrict__ xr,
    int XS, const float* __restrict__ eattr, const unsigned short* __restrict__ WeT,
    const float* __restrict__ att, const int* __restrict__ perm,
    const int* __restrict__ srcs, const int* __restrict__ dsts,
    float* __restrict__ logits, int E) {
    constexpr int EB = (HC == 1024) ? 8 : 16;
    constexpr int LDE = HC + 8;
    __shared__ unsigned short ef_s[EB * LDE];
    __shared__ int src_s[EB], dst_s[EB], e_s[16];
    __shared__ float logit_s[EB * 4];

    int tid = threadIdx.x;
    int s0 = blockIdx.x * EB;
    int lane = tid & 63, w = tid >> 6;
    int l15 = lane & 15, quad = lane >> 4;

    if (tid < EB) { src_s[tid] = srcs[s0 + tid]; dst_s[tid] = dsts[s0 + tid]; }
    if (tid < 16) e_s[tid] = perm[s0 + (tid & (EB - 1))];
    __syncthreads();

    // A-frag: eattr rows (K zero-padded 16->32); trunc conversion
    u8x16 a;
    if (quad < 2) {
        const float* ap = &eattr[(size_t)e_s[l15] * 16 + quad * 8];
        float4 a0 = *(const float4*)ap;
        float4 a1 = *(const float4*)(ap + 4);
        a.u[0] = f2bits_trunc(a0.x); a.u[1] = f2bits_trunc(a0.y);
        a.u[2] = f2bits_trunc(a0.z); a.u[3] = f2bits_trunc(a0.w);
        a.u[4] = f2bits_trunc(a1.x); a.u[5] = f2bits_trunc(a1.y);
        a.u[6] = f2bits_trunc(a1.z); a.u[7] = f2bits_trunc(a1.w);
    } else {
#pragma unroll
        for (int j = 0; j < 8; j++) a.u[j] = 0;
    }

    // Phase 1: ef = eattr @ We -> LDS (bf16 trunc; rows >= EB discarded)
    for (int t = w; t < HC / 16; t += 4) {
        int col = t * 16 + l15;
        u8x16 b;
        if (quad < 2) *(uint4*)b.u = *(const uint4*)&WeT[(size_t)col * 16 + quad * 8];
        else {
#pragma unroll
            for (int j = 0; j < 8; j++) b.u[j] = 0;
        }
        floatx4 c = {0.f, 0.f, 0.f, 0.f};
        c = __builtin_amdgcn_mfma_f32_16x16x32_bf16(a.v, b.v, c, 0, 0, 0);
#pragma unroll
        for (int r = 0; r < 4; r++) {
            int row = quad * 4 + r;
            if (row < EB) ef_s[row * LDE + col] = f2bits_trunc(c[r]);
        }
    }
    __syncthreads();

    // Phase 2: 16-lane quarters; lane covers 16 channels (2x uint4 = 32B).
    int qt = lane >> 4, ql = lane & 15;
    if constexpr (HC == 1024) {
        int c0 = w * 256 + ql * 16;           // head w's channels
        float2v a06[8], a04[8];
#pragma unroll
        for (int j = 0; j < 8; j++) {
            float x0 = att[c0 + 2 * j], x1 = att[c0 + 2 * j + 1];
            a06[j] = (float2v){0.6f * x0, 0.6f * x1};
            a04[j] = (float2v){0.4f * x0, 0.4f * x1};
        }
        int prevd = -1;
        float2v r[8];
#pragma unroll
        for (int j = 0; j < 8; j++) r[j] = (float2v){0.f, 0.f};
#pragma unroll
        for (int pp = 0; pp < 2; pp++) {
            int e = qt * 2 + pp;              // adjacent slots per quarter -> dedup
            int src = src_s[e], dst = dst_s[e];
            if (dst != prevd) {
                uint4 wr0 = *(const uint4*)&xr[(size_t)dst * XS + c0];
                uint4 wr1 = *(const uint4*)&xr[(size_t)dst * XS + c0 + 8];
                r[0] = cvt2(wr0.x); r[1] = cvt2(wr0.y); r[2] = cvt2(wr0.z); r[3] = cvt2(wr0.w);
                r[4] = cvt2(wr1.x); r[5] = cvt2(wr1.y); r[6] = cvt2(wr1.z); r[7] = cvt2(wr1.w);
                prevd = dst;
            }
            uint4 wl0 = *(const uint4*)&xl[(size_t)src * XS + c0];
            uint4 wl1 = *(const uint4*)&xl[(size_t)src * XS + c0 + 8];
            uint4 wf0 = *(const uint4*)&ef_s[e * LDE + c0];
            uint4 wf1 = *(const uint4*)&ef_s[e * LDE + c0 + 8];
            float2v v, p2 = {0.f, 0.f};
            v = cvt2(wl0.x) + r[0] + cvt2(wf0.x); p2 += a06[0] * v + a04[0] * absv(v);
            v = cvt2(wl0.y) + r[1] + cvt2(wf0.y); p2 += a06[1] * v + a04[1] * absv(v);
            v = cvt2(wl0.z) + r[2] + cvt2(wf0.z); p2 += a06[2] * v + a04[2] * absv(v);
            v = cvt2(wl0.w) + r[3] + cvt2(wf0.w); p2 += a06[3] * v + a04[3] * absv(v);
            v = cvt2(wl1.x) + r[4] + cvt2(wf1.x); p2 += a06[4] * v + a04[4] * absv(v);
            v = cvt2(wl1.y) + r[5] + cvt2(wf1.y); p2 += a06[5] * v + a04[5] * absv(v);
            v = cvt2(wl1.z) + r[6] + cvt2(wf1.z); p2 += a06[6] * v + a04[6] * absv(v);
            v = cvt2(wl1.w) + r[7] + cvt2(wf1.w); p2 += a06[7] * v + a04[7] * absv(v);
            float part = p2.x + p2.y;
            part += __shfl_xor(part, 1, 64);
            part += __shfl_xor(part, 2, 64);
            part += __shfl_xor(part, 4, 64);
            part += __shfl_xor(part, 8, 64);
            if (ql == 0) logit_s[e * 4 + w] = part;
        }
    } else {
        // one pass: quarter qt owns edge w*4+qt; lane covers 16 of 256 ch.
        int e = w * 4 + qt;
        int c0 = ql * 16;
        int hd = ql >> 2;                     // lane's head (16ch*4lanes = 64ch/head)
        float2v a06[8], a04[8];
#pragma unroll
        for (int j = 0; j < 8; j++) {
            float x0 = att[c0 + 2 * j], x1 = att[c0 + 2 * j + 1];
            a06[j] = (float2v){0.6f * x0, 0.6f * x1};
            a04[j] = (float2v){0.4f * x0, 0.4f * x1};
        }
        int src = src_s[e], dst = dst_s[e];
        uint4 wr0 = *(const uint4*)&xr[(size_t)dst * XS + c0];
        uint4 wr1 = *(const uint4*)&xr[(size_t)dst * XS + c0 + 8];
        uint4 wl0 = *(const uint4*)&xl[(size_t)src * XS + c0];
        uint4 wl1 = *(const uint4*)&xl[(size_t)src * XS + c0 + 8];
        uint4 wf0 = *(const uint4*)&ef_s[e * LDE + c0];
        uint4 wf1 = *(const uint4*)&ef_s[e * LDE + c0 + 8];
        float2v v, p2 = {0.f, 0.f};
        v = cvt2(wl0.x) + cvt2(wr0.x) + cvt2(wf0.x); p2 += a06[0] * v + a04[0] * absv(v);
        v = cvt2(wl0.y) + cvt2(wr0.y) + cvt2(wf0.y); p2 += a06[1] * v + a04[1] * absv(v);
        v = cvt2(wl0.z) + cvt2(wr0.z) + cvt2(wf0.z); p2 += a06[2] * v + a04[2] * absv(v);
        v = cvt2(wl0.w) + cvt2(wr0.w) + cvt2(wf0.w); p2 += a06[3] * v + a04[3] * absv(v);
        v = cvt2(wl1.x) + cvt2(wr1.x) + cvt2(wf1.x); p2 += a06[4] * v + a04[4] * absv(v);
        v = cvt2(wl1.y) + cvt2(wr1.y) + cvt2(wf1.y); p2 += a06[5] * v + a04[5] * absv(v);
        v = cvt2(wl1.z) + cvt2(wr1.z) + cvt2(wf1.z); p2 += a06[6] * v + a04[6] * absv(v);
        v = cvt2(wl1.w) + cvt2(wr1.w) + cvt2(wf1.w); p2 += a06[7] * v + a04[7] * absv(v);
        float part = p2.x + p2.y;
        part += __shfl_xor(part, 1, 64);      // sum 4 lanes of same head
        part += __shfl_xor(part, 2, 64);
        if ((ql & 3) == 0) logit_s[e * 4 + hd] = part;
    }
    __syncthreads();
    if (tid < EB * 4) logits[(size_t)s0 * 4 + tid] = logit_s[tid];
}

// ---------------- node aggregation: WPN waves per node, 2-unrolled gather ----
template<int HC, int WPN, bool OUT_BF16>
__global__ __launch_bounds__(256) void node_agg_wave_kernel(
    const unsigned short* __restrict__ xl, int XS, const float* __restrict__ logits,
    const int* __restrict__ srcs, const int* __restrict__ offsets,
    const float* __restrict__ bias, void* __restrict__ outv) {
    constexpr int J = HC / (64 * WPN);    // 8 (L1) or 4 (L2)
    int tid = threadIdx.x;
    int wid = tid >> 6, lane = tid & 63;
    int n, ha;
    if constexpr (WPN == 2) { n = blockIdx.x * 2 + (wid >> 1); ha = wid & 1; }
    else { n = blockIdx.x * 4 + wid; ha = 0; }
    int o0 = offsets[n];
    int deg = offsets[n + 1] - o0;

    int hl;
    float m = -3.0e38f, s = 0.f;
    if constexpr (WPN == 2) {
        hl = ha * 2 + (lane >> 5);
        int p = lane & 31;
        for (int i = p; i < deg; i += 32)
            m = fmaxf(m, logits[(size_t)(o0 + i) * 4 + hl]);
        m = fmaxf(m, __shfl_xor(m, 1, 64));
        m = fmaxf(m, __shfl_xor(m, 2, 64));
        m = fmaxf(m, __shfl_xor(m, 4, 64));
        m = fmaxf(m, __shfl_xor(m, 8, 64));
        m = fmaxf(m, __shfl_xor(m, 16, 64));
        for (int i = p; i < deg; i += 32)
            s += __expf(logits[(size_t)(o0 + i) * 4 + hl] - m);
        s += __shfl_xor(s, 1, 64);
        s += __shfl_xor(s, 2, 64);
        s += __shfl_xor(s, 4, 64);
        s += __shfl_xor(s, 8, 64);
        s += __shfl_xor(s, 16, 64);
    } else {
        hl = lane >> 4;
        int p = lane & 15;
        for (int i = p; i < deg; i += 16)
            m = fmaxf(m, logits[(size_t)(o0 + i) * 4 + hl]);
        m = fmaxf(m, __shfl_xor(m, 1, 64));
        m = fmaxf(m, __shfl_xor(m, 2, 64));
        m = fmaxf(m, __shfl_xor(m, 4, 64));
        m = fmaxf(m, __shfl_xor(m, 8, 64));
        for (int i = p; i < deg; i += 16)
            s += __expf(logits[(size_t)(o0 + i) * 4 + hl] - m);
        s += __shfl_xor(s, 1, 64);
        s += __shfl_xor(s, 2, 64);
        s += __shfl_xor(s, 4, 64);
        s += __shfl_xor(s, 8, 64);
    }
    float inv = 1.f / (s + 1e-16f);

    int c0 = ha * (HC / WPN) + lane * J;
    float acc[J];
#pragma unroll
    for (int v = 0; v < J; v++) acc[v] = bias[c0 + v];

    int i = 0;
    for (; i + 2 <= deg; i += 2) {
        int sl0 = o0 + i, sl1 = o0 + i + 1;
        int src0 = srcs[sl0], src1 = srcs[sl1];
        const unsigned short* row0 = &xl[(size_t)src0 * XS + c0];
        const unsigned short* row1 = &xl[(size_t)src1 * XS + c0];
        float alpha0 = __expf(logits[(size_t)sl0 * 4 + hl] - m) * inv;
        float alpha1 = __expf(logits[(size_t)sl1 * 4 + hl] - m) * inv;
        if constexpr (J == 8) {
            u8x16 a0, a1;
            a0.v = *(const short8*)row0;
            a1.v = *(const short8*)row1;
#pragma unroll
            for (int v = 0; v < 8; v++) acc[v] += alpha0 * bits2f(a0.u[v]) + alpha1 * bits2f(a1.u[v]);
        } else {
            unsigned short u0[4], u1[4];
            *(ushort4*)u0 = *(const ushort4*)row0;
            *(ushort4*)u1 = *(const ushort4*)row1;
#pragma unroll
            for (int v = 0; v < 4; v++) acc[v] += alpha0 * bits2f(u0[v]) + alpha1 * bits2f(u1[v]);
        }
    }
    if (i < deg) {
        int sl = o0 + i;
        float alpha = __expf(logits[(size_t)sl * 4 + hl] - m) * inv;
        int src = srcs[sl];
        const unsigned short* row = &xl[(size_t)src * XS + c0];
        if constexpr (J == 8) {
            u8x16 a0; a0.v = *(const short8*)row;
#pragma unroll
            for (int v = 0; v < 8; v++) acc[v] += alpha * bits2f(a0.u[v]);
        } else {
            unsigned short us[4];
            *(ushort4*)us = *(const ushort4*)row;
#pragma unroll
            for (int v = 0; v < 4; v++) acc[v] += alpha * bits2f(us[v]);
        }
    }

    if constexpr (OUT_BF16) {
        unsigned short* o = (unsigned short*)outv;
        u8x16 w0;
#pragma unroll
        for (int v = 0; v < 8; v++) w0.u[v] = f2bits(fmaxf(acc[v], 0.f));
        *(short8*)&o[(size_t)n * HC + c0] = w0.v;
    } else {
        float* o = (float*)outv;
        float4 f;
        f.x = fmaxf(acc[0], 0.f); f.y = fmaxf(acc[1], 0.f);
        f.z = fmaxf(acc[2], 0.f); f.w = fmaxf(acc[3], 0.f);
        *(float4*)&o[(size_t)n * HC + c0] = f;
    }
}

// ---------------- MLP head ----------------
__global__ __launch_bounds__(64) void mlp_head_kernel(
    const float* __restrict__ h2, const int* __restrict__ nnod,
    const float* __restrict__ w1, const float* __restrict__ b1,
    const float* __restrict__ w2, const float* __restrict__ b2,
    float* __restrict__ out, int B) {
    int b = blockIdx.x, tid = threadIdx.x;
    int sum = 0;
    for (int j = tid; j <= b; j += 64) sum += nnod[j];
#pragma unroll
    for (int off = 32; off > 0; off >>= 1) sum += __shfl_xor(sum, off, 64);
    int node = sum - 1;
    __shared__ float mast[256];
    for (int i = tid; i < 256; i += 64) mast[i] = h2[(size_t)node * 256 + i];
    __syncthreads();
    float z = 0.f;
    for (int k = 0; k < 256; k++) z += mast[k] * w1[k * 64 + tid];
    z += b1[tid];
    z = z > 0.f ? z : 0.f;
    float p = z * w2[tid];
#pragma unroll
    for (int off = 32; off > 0; off >>= 1) p += __shfl_down(p, off, 64);
    if (tid == 0) out[b] = p + b2[0];
}

extern "C" void kernel_launch(void* const* d_in, const int* in_sizes, int n_in,
                              void* d_out, int out_size, void* d_ws, size_t ws_size,
                              hipStream_t stream) {
    const float* x     = (const float*)d_in[0];
    const int*   ei    = (const int*)d_in[1];
    const float* eattr = (const float*)d_in[2];
    const int*   nnod  = (const int*)d_in[3];
    const float* Wl1 = (const float*)d_in[4];
    const float* bl1 = (const float*)d_in[5];
    const float* Wr1 = (const float*)d_in[6];
    const float* br1 = (const float*)d_in[7];
    const float* We1 = (const float*)d_in[8];
    const float* att1= (const float*)d_in[9];
    const float* b1  = (const float*)d_in[10];
    const float* Wl2 = (const float*)d_in[11];
    const float* bl2 = (const float*)d_in[12];
    const float* Wr2 = (const float*)d_in[13];
    const float* br2 = (const float*)d_in[14];
    const float* We2 = (const float*)d_in[15];
    const float* att2= (const float*)d_in[16];
    const float* b2  = (const float*)d_in[17];
    const float* fc1w= (const float*)d_in[18];
    const float* fc1b= (const float*)d_in[19];
    const float* fc2w= (const float*)d_in[20];
    const float* fc2b= (const float*)d_in[21];
    float* out = (float*)d_out;

    const int N = NN, E = EE, B = BB;

    // ---------- workspace layout ----------
    char* base = (char*)d_ws;
    const size_t NB1 = (size_t)N * 1024 * 2;
    unsigned short* xl1   = (unsigned short*)base;
    unsigned short* xlxr2 = (unsigned short*)base;                       // [N][512]
    float*          h2    = (float*)(base + (size_t)N * 512 * 2);        // [N][256] f32
    unsigned short* xr1 = (unsigned short*)(base + NB1);
    unsigned short* h1  = (unsigned short*)(base + NB1);
    char* t = base + 2 * NB1;
    float* logits = (float*)t;        t += (size_t)E * 4 * sizeof(float);
    int* counts   = (int*)t;          t += (size_t)N * sizeof(int);
    int* offsets  = (int*)t;          t += (size_t)(N + 1) * sizeof(int);
    int* woff     = (int*)t;          t += (size_t)N * sizeof(int);
    int* perm     = (int*)t;          t += (size_t)E * sizeof(int);
    int* srcs     = (int*)t;          t += (size_t)E * sizeof(int);
    int* dsts     = (int*)t;          t += (size_t)E * sizeof(int);
    t = (char*)(((uintptr_t)t + 63) & ~(uintptr_t)63);
    unsigned short* xb    = (unsigned short*)t; t += (size_t)N * 128 * 2;
    unsigned short* wtl1  = (unsigned short*)t; t += (size_t)1024 * 128 * 2;   // contiguous with
    unsigned short* wtr1  = (unsigned short*)t; t += (size_t)1024 * 128 * 2;   //  wtl1 -> [2048][128]
    unsigned short* wtlr2 = (unsigned short*)t; t += (size_t)512 * 1024 * 2;
    unsigned short* weT1  = (unsigned short*)t; t += (size_t)1024 * 16 * 2;
    unsigned short* weT2  = (unsigned short*)t; t += (size_t)256 * 16 * 2;
    float* blr2           = (float*)t;          t += (size_t)512 * sizeof(float);
    size_t required = (size_t)(t - base);
    if (ws_size < required) return;   // guard: absmax-fail instead of abort

    dim3 blk(256);

    // ---------- CSR build ----------
    zero_int_kernel<<<(N + 255) / 256, blk, 0, stream>>>(counts, N);
    hist_kernel<<<(E + 255) / 256, blk, 0, stream>>>(ei, counts, E);
    scan_kernel<<<1, 1024, 0, stream>>>(counts, offsets, woff, N);
    scatter_kernel<<<(E + 255) / 256, blk, 0, stream>>>(ei, woff, perm, srcs, dsts, E);

    // ---------- conversions ----------
    convert_bf16_kernel<<<(N * 128 + 255) / 256, blk, 0, stream>>>(x, xb, N * 128);
    convert_weights_kernel<<<3154, blk, 0, stream>>>(Wl1, Wr1, Wl2, Wr2, We1, We2, bl2, br2,
                                                     wtl1, wtr1, wtlr2, weT1, weT2, blr2);

    // ---------- layer 1 (fused xl|xr GEMM, Ntot=2048, split write) ----------
    {
        dim3 g1(2048 / 128, N / 128);
        mfma_gemm_bt_kernel<<<g1, blk, 0, stream>>>(xb, wtl1, bl1, br1, xl1, xr1, N, 128, 1024);
    }
    edge_score_v9_kernel<1024><<<E / 8, blk, 0, stream>>>(xl1, xr1, 1024, eattr, weT1, att1, perm, srcs, dsts, logits, E);
    node_agg_wave_kernel<1024, 2, true><<<N / 2, blk, 0, stream>>>(xl1, 1024, logits, srcs, offsets, b1, h1);

    // ---------- layer 2 (fused xl|xr GEMM, N=512) ----------
    {
        dim3 g2(512 / 128, N / 128);
        mfma_gemm_bt_kernel<<<g2, blk, 0, stream>>>(h1, wtlr2, blr2, blr2, xlxr2, xlxr2, N, 1024, 512);
    }
    edge_score_v9_kernel<256><<<E / 16, blk, 0, stream>>>(xlxr2, xlxr2 + 256, 512, eattr, weT2, att2, perm, srcs, dsts, logits, E);
    node_agg_wave_kernel<256, 1, false><<<N / 4, blk, 0, stream>>>(xlxr2, 512, logits, srcs, offsets, b2, h2);

    // ---------- head ----------
    mlp_head_kernel<<<B, 64, 0, stream>>>(h2, nnod, fc1w, fc1b, fc2w, fc2b, out, B);
}

// Round 14
// 780.015 us; speedup vs baseline: 1.0453x; 1.0453x over previous
//
#include <hip/hip_runtime.h>
#include <hip/hip_bf16.h>
#include <cmath>

#define NN 49920
#define EE 200000
#define BB 128

typedef __attribute__((ext_vector_type(8))) short short8;
typedef __attribute__((ext_vector_type(4))) float floatx4;
typedef __attribute__((ext_vector_type(2))) float float2v;

union u8x16 { short8 v; unsigned short u[8]; };

__device__ __forceinline__ float bits2f(unsigned short u) {
    union { unsigned int i; float f; } c; c.i = ((unsigned int)u) << 16; return c.f;
}
__device__ __forceinline__ unsigned short f2bits(float f) {
    union { float f; unsigned int i; } c; c.f = f;
    unsigned int x = c.i;
    return (unsigned short)((x + 0x7fffu + ((x >> 16) & 1u)) >> 16);   // RNE
}
__device__ __forceinline__ unsigned short f2bits_trunc(float f) {
    union { float f; unsigned int i; } c; c.f = f;
    return (unsigned short)(c.i >> 16);                               // truncate (1 op)
}
__device__ __forceinline__ float2v cvt2(unsigned int w) {
    union { unsigned int i; float f; } lo, hi;
    lo.i = w << 16; hi.i = w & 0xffff0000u;
    return (float2v){lo.f, hi.f};
}
__device__ __forceinline__ float2v absv(float2v v) {
    union { float2v f; unsigned int u[2]; } c; c.f = v;
    c.u[0] &= 0x7fffffffu; c.u[1] &= 0x7fffffffu;
    return c.f;
}

typedef const __attribute__((address_space(1))) void* gvp;
typedef __attribute__((address_space(3))) void* lvp;
__device__ __forceinline__ void gll16(const void* g, void* l) {
    __builtin_amdgcn_global_load_lds((gvp)g, (lvp)l, 16, 0, 0);
}

// ---------------- small utility kernels ----------------
__global__ void zero_int_kernel(int* __restrict__ p, int n) {
    int i = blockIdx.x * blockDim.x + threadIdx.x;
    if (i < n) p[i] = 0;
}

__global__ void convert_bf16_kernel(const float* __restrict__ src, unsigned short* __restrict__ dst, int n) {
    int i = blockIdx.x * blockDim.x + threadIdx.x;
    if (i < n) dst[i] = f2bits(src[i]);
}

// fused conversion of ALL weights
__global__ void convert_weights_kernel(
    const float* __restrict__ Wl1, const float* __restrict__ Wr1,
    const float* __restrict__ Wl2, const float* __restrict__ Wr2,
    const float* __restrict__ We1, const float* __restrict__ We2,
    const float* __restrict__ bl2, const float* __restrict__ br2,
    unsigned short* __restrict__ wtl1, unsigned short* __restrict__ wtr1,
    unsigned short* __restrict__ wtlr2, unsigned short* __restrict__ weT1,
    unsigned short* __restrict__ weT2, float* __restrict__ blr2) {
    int b = blockIdx.x, tid = threadIdx.x;
    if (b < 1024) {                       // Wl1/Wr1 [128][1024] -> WT [1024][128]
        const float* W = (b < 512) ? Wl1 : Wr1;
        unsigned short* WT = (b < 512) ? wtl1 : wtr1;
        int i = ((b & 511) << 8) + tid;
        int n = i >> 7, k = i & 127;
        WT[i] = f2bits(W[k * 1024 + n]);
    } else if (b < 3072) {                // Wl2/Wr2 [1024][256] -> wtlr2 [512][1024]
        int bb = b - 1024;
        const float* W = (bb < 1024) ? Wl2 : Wr2;
        int i = ((bb & 1023) << 8) + tid;
        int n = i >> 10, k = i & 1023;
        int off = (bb < 1024) ? 0 : 262144;
        wtlr2[off + i] = f2bits(W[k * 256 + n]);
    } else if (b < 3136) {                // We1 [16][1024] -> weT1 [1024][16]
        int i = ((b - 3072) << 8) + tid;
        int col = i >> 4, k = i & 15;
        weT1[i] = f2bits(We1[k * 1024 + col]);
    } else if (b < 3152) {                // We2 [16][256] -> weT2 [256][16]
        int i = ((b - 3136) << 8) + tid;
        int col = i >> 4, k = i & 15;
        weT2[i] = f2bits(We2[k * 256 + col]);
    } else {                              // blr2 = bl2 | br2 (512 f32)
        int i = ((b - 3152) << 8) + tid;
        if (i < 512) blr2[i] = (i < 256) ? bl2[i] : br2[i - 256];
    }
}

// ---------------- bf16 MFMA GEMM (B^T input, async staging, split output) ----
__global__ __launch_bounds__(256) void mfma_gemm_bt_kernel(
    const unsigned short* __restrict__ A, const unsigned short* __restrict__ WT,
    const float* __restrict__ bias, const float* __restrict__ bias2,
    unsigned short* __restrict__ C, unsigned short* __restrict__ C2,
    int M, int K, int Nout) {
    __shared__ unsigned short As[128 * 32];
    __shared__ unsigned short Bs[128 * 32];
    int tid = threadIdx.x;
    int lane = tid & 63, wid = tid >> 6;
    int gm0 = blockIdx.y * 128, gn0 = blockIdx.x * 128;
    int wm = (wid & 1) * 64, wn = (wid >> 1) * 64;
    int l15 = lane & 15, quad = lane >> 4;
    int r0 = wid * 32;
    int gr = r0 + (lane >> 2);
    int kc = (lane & 3) * 8;

    floatx4 acc[4][4];
#pragma unroll
    for (int i = 0; i < 4; i++)
#pragma unroll
        for (int j = 0; j < 4; j++)
#pragma unroll
            for (int r = 0; r < 4; r++) acc[i][j][r] = 0.f;

    const unsigned short* Ap0 = &A[(size_t)(gm0 + gr) * K + kc];
    const unsigned short* Ap1 = Ap0 + (size_t)16 * K;
    const unsigned short* Bp0 = &WT[(size_t)(gn0 + gr) * K + kc];
    const unsigned short* Bp1 = Bp0 + (size_t)16 * K;
    unsigned short* as0 = &As[r0 * 32];
    unsigned short* as1 = &As[(r0 + 16) * 32];
    unsigned short* bs0 = &Bs[r0 * 32];
    unsigned short* bs1 = &Bs[(r0 + 16) * 32];

    for (int k0 = 0; k0 < K; k0 += 32) {
        __syncthreads();
        gll16(Ap0 + k0, as0);
        gll16(Ap1 + k0, as1);
        gll16(Bp0 + k0, bs0);
        gll16(Bp1 + k0, bs1);
        __syncthreads();
        short8 af[4], bfr[4];
#pragma unroll
        for (int i = 0; i < 4; i++)
            af[i] = *(const short8*)&As[(wm + 16 * i + l15) * 32 + quad * 8];
#pragma unroll
        for (int j = 0; j < 4; j++)
            bfr[j] = *(const short8*)&Bs[(wn + 16 * j + l15) * 32 + quad * 8];
#pragma unroll
        for (int i = 0; i < 4; i++)
#pragma unroll
            for (int j = 0; j < 4; j++)
                acc[i][j] = __builtin_amdgcn_mfma_f32_16x16x32_bf16(af[i], bfr[j], acc[i][j], 0, 0, 0);
    }

    unsigned short* Cw = C;
    const float* bp = bias;
    int colb = gn0 + wn + l15;
    if (gn0 >= Nout) { Cw = C2; bp = bias2; colb -= Nout; }
#pragma unroll
    for (int i = 0; i < 4; i++) {
#pragma unroll
        for (int j = 0; j < 4; j++) {
            int col = colb + 16 * j;
            float bv = bp[col];
#pragma unroll
            for (int r = 0; r < 4; r++) {
                int rrow = gm0 + wm + 16 * i + quad * 4 + r;
                Cw[(size_t)rrow * Nout + col] = f2bits(acc[i][j][r] + bv);
            }
        }
    }
}

// ---------------- CSR build ----------------
__global__ void hist_kernel(const int* __restrict__ ei, int* __restrict__ counts, int E) {
    int e = blockIdx.x * blockDim.x + threadIdx.x;
    if (e < E) atomicAdd(&counts[ei[E + e]], 1);
}

__global__ __launch_bounds__(1024) void scan_kernel(
    const int* __restrict__ counts, int* __restrict__ offsets,
    int* __restrict__ woff, int N) {
    __shared__ int partial[1024];
    int tid = threadIdx.x;
    const int CH = (N + 1023) >> 10;
    int b0 = tid * CH;
    int s = 0;
    for (int i = 0; i < CH; i++) { int idx = b0 + i; if (idx < N) s += counts[idx]; }
    partial[tid] = s;
    __syncthreads();
    if (tid == 0) {
        int acc = 0;
        for (int i = 0; i < 1024; i++) { int t = partial[i]; partial[i] = acc; acc += t; }
        offsets[N] = acc;
    }
    __syncthreads();
    int run = partial[tid];
    for (int i = 0; i < CH; i++) {
        int idx = b0 + i;
        if (idx < N) { offsets[idx] = run; woff[idx] = run; run += counts[idx]; }
    }
}

__global__ void scatter_kernel(const int* __restrict__ ei, int* __restrict__ woff,
                               int* __restrict__ perm, int* __restrict__ srcs,
                               int* __restrict__ dsts, int E) {
    int e = blockIdx.x * blockDim.x + threadIdx.x;
    if (e < E) {
        int d = ei[E + e];
        int slot = atomicAdd(&woff[d], 1);
        perm[slot] = e;
        srcs[slot] = ei[e];
        dsts[slot] = d;
    }
}

// ---------------- edge scoring v10: quarter-wave edges, lane-contiguous loads -
// Lane covers 16 ch as TWO lane-contiguous 128-ch blocks (cA=base+ql*8,
// cB=cA+128) -> every uint4 LDS/global read is 16B/lane contiguous (0-conflict,
// per v8 evidence) while keeping v9's short reduce chains.
template<int HC>
__global__ __launch_bounds__(256) void edge_score_v10_kernel(
    const unsigned short* __restrict__ xl, const unsigned short* __restrict__ xr,
    int XS, const float* __restrict__ eattr, const unsigned short* __restrict__ WeT,
    const float* __restrict__ att, const int* __restrict__ perm,
    const int* __restrict__ srcs, const int* __restrict__ dsts,
    float* __restrict__ logits, int E) {
    constexpr int EB = (HC == 1024) ? 8 : 16;
    constexpr int LDE = HC + 8;
    __shared__ unsigned short ef_s[EB * LDE];
    __shared__ int src_s[EB], dst_s[EB], e_s[16];
    __shared__ float logit_s[EB * 4];

    int tid = threadIdx.x;
    int s0 = blockIdx.x * EB;
    int lane = tid & 63, w = tid >> 6;
    int l15 = lane & 15, quad = lane >> 4;

    if (tid < EB) { src_s[tid] = srcs[s0 + tid]; dst_s[tid] = dsts[s0 + tid]; }
    if (tid < 16) e_s[tid] = perm[s0 + (tid & (EB - 1))];
    __syncthreads();

    // A-frag: eattr rows (K zero-padded 16->32); trunc conversion
    u8x16 a;
    if (quad < 2) {
        const float* ap = &eattr[(size_t)e_s[l15] * 16 + quad * 8];
        float4 a0 = *(const float4*)ap;
        float4 a1 = *(const float4*)(ap + 4);
        a.u[0] = f2bits_trunc(a0.x); a.u[1] = f2bits_trunc(a0.y);
        a.u[2] = f2bits_trunc(a0.z); a.u[3] = f2bits_trunc(a0.w);
        a.u[4] = f2bits_trunc(a1.x); a.u[5] = f2bits_trunc(a1.y);
        a.u[6] = f2bits_trunc(a1.z); a.u[7] = f2bits_trunc(a1.w);
    } else {
#pragma unroll
        for (int j = 0; j < 8; j++) a.u[j] = 0;
    }

    // Phase 1: ef = eattr @ We -> LDS (bf16 trunc; rows >= EB discarded)
    for (int t = w; t < HC / 16; t += 4) {
        int col = t * 16 + l15;
        u8x16 b;
        if (quad < 2) *(uint4*)b.u = *(const uint4*)&WeT[(size_t)col * 16 + quad * 8];
        else {
#pragma unroll
            for (int j = 0; j < 8; j++) b.u[j] = 0;
        }
        floatx4 c = {0.f, 0.f, 0.f, 0.f};
        c = __builtin_amdgcn_mfma_f32_16x16x32_bf16(a.v, b.v, c, 0, 0, 0);
#pragma unroll
        for (int r = 0; r < 4; r++) {
            int row = quad * 4 + r;
            if (row < EB) ef_s[row * LDE + col] = f2bits_trunc(c[r]);
        }
    }
    __syncthreads();

    int qt = lane >> 4, ql = lane & 15;
    if constexpr (HC == 1024) {
        // quarter qt handles edges qt*2, qt*2+1; both 128-ch blocks in head w
        int cA = w * 256 + ql * 8;
        int cB = cA + 128;
        float2v a06[8], a04[8];
#pragma unroll
        for (int j = 0; j < 4; j++) {
            float x0 = att[cA + 2 * j], x1 = att[cA + 2 * j + 1];
            a06[j] = (float2v){0.6f * x0, 0.6f * x1};
            a04[j] = (float2v){0.4f * x0, 0.4f * x1};
        }
#pragma unroll
        for (int j = 0; j < 4; j++) {
            float x0 = att[cB + 2 * j], x1 = att[cB + 2 * j + 1];
            a06[4 + j] = (float2v){0.6f * x0, 0.6f * x1};
            a04[4 + j] = (float2v){0.4f * x0, 0.4f * x1};
        }
        int prevd = -1;
        float2v r[8];
#pragma unroll
        for (int j = 0; j < 8; j++) r[j] = (float2v){0.f, 0.f};
#pragma unroll
        for (int pp = 0; pp < 2; pp++) {
            int e = qt * 2 + pp;              // adjacent slots -> xr dedup
            int src = src_s[e], dst = dst_s[e];
            if (dst != prevd) {
                uint4 wr0 = *(const uint4*)&xr[(size_t)dst * XS + cA];
                uint4 wr1 = *(const uint4*)&xr[(size_t)dst * XS + cB];
                r[0] = cvt2(wr0.x); r[1] = cvt2(wr0.y); r[2] = cvt2(wr0.z); r[3] = cvt2(wr0.w);
                r[4] = cvt2(wr1.x); r[5] = cvt2(wr1.y); r[6] = cvt2(wr1.z); r[7] = cvt2(wr1.w);
                prevd = dst;
            }
            uint4 wl0 = *(const uint4*)&xl[(size_t)src * XS + cA];
            uint4 wl1 = *(const uint4*)&xl[(size_t)src * XS + cB];
            uint4 wf0 = *(const uint4*)&ef_s[e * LDE + cA];
            uint4 wf1 = *(const uint4*)&ef_s[e * LDE + cB];
            float2v v, p2 = {0.f, 0.f};
            v = cvt2(wl0.x) + r[0] + cvt2(wf0.x); p2 += a06[0] * v + a04[0] * absv(v);
            v = cvt2(wl0.y) + r[1] + cvt2(wf0.y); p2 += a06[1] * v + a04[1] * absv(v);
            v = cvt2(wl0.z) + r[2] + cvt2(wf0.z); p2 += a06[2] * v + a04[2] * absv(v);
            v = cvt2(wl0.w) + r[3] + cvt2(wf0.w); p2 += a06[3] * v + a04[3] * absv(v);
            v = cvt2(wl1.x) + r[4] + cvt2(wf1.x); p2 += a06[4] * v + a04[4] * absv(v);
            v = cvt2(wl1.y) + r[5] + cvt2(wf1.y); p2 += a06[5] * v + a04[5] * absv(v);
            v = cvt2(wl1.z) + r[6] + cvt2(wf1.z); p2 += a06[6] * v + a04[6] * absv(v);
            v = cvt2(wl1.w) + r[7] + cvt2(wf1.w); p2 += a06[7] * v + a04[7] * absv(v);
            float part = p2.x + p2.y;
            part += __shfl_xor(part, 1, 64);
            part += __shfl_xor(part, 2, 64);
            part += __shfl_xor(part, 4, 64);
            part += __shfl_xor(part, 8, 64);
            if (ql == 0) logit_s[e * 4 + w] = part;
        }
    } else {
        // one pass: quarter qt owns edge w*4+qt. Block A = heads {0,1} (ch ql*8),
        // block B = heads {2,3} (ch 128+ql*8). Two partials, 3-step reduces.
        int e = w * 4 + qt;
        int cA = ql * 8;
        int cB = 128 + ql * 8;
        float2v a06[8], a04[8];
#pragma unroll
        for (int j = 0; j < 4; j++) {
            float x0 = att[cA + 2 * j], x1 = att[cA + 2 * j + 1];
            a06[j] = (float2v){0.6f * x0, 0.6f * x1};
            a04[j] = (float2v){0.4f * x0, 0.4f * x1};
        }
#pragma unroll
        for (int j = 0; j < 4; j++) {
            float x0 = att[cB + 2 * j], x1 = att[cB + 2 * j + 1];
            a06[4 + j] = (float2v){0.6f * x0, 0.6f * x1};
            a04[4 + j] = (float2v){0.4f * x0, 0.4f * x1};
        }
        int src = src_s[e], dst = dst_s[e];
        uint4 wr0 = *(const uint4*)&xr[(size_t)dst * XS + cA];
        uint4 wr1 = *(const uint4*)&xr[(size_t)dst * XS + cB];
        uint4 wl0 = *(const uint4*)&xl[(size_t)src * XS + cA];
        uint4 wl1 = *(const uint4*)&xl[(size_t)src * XS + cB];
        uint4 wf0 = *(const uint4*)&ef_s[e * LDE + cA];
        uint4 wf1 = *(const uint4*)&ef_s[e * LDE + cB];
        float2v v, pa = {0.f, 0.f}, pb = {0.f, 0.f};
        v = cvt2(wl0.x) + cvt2(wr0.x) + cvt2(wf0.x); pa += a06[0] * v + a04[0] * absv(v);
        v = cvt2(wl0.y) + cvt2(wr0.y) + cvt2(wf0.y); pa += a06[1] * v + a04[1] * absv(v);
        v = cvt2(wl0.z) + cvt2(wr0.z) + cvt2(wf0.z); pa += a06[2] * v + a04[2] * absv(v);
        v = cvt2(wl0.w) + cvt2(wr0.w) + cvt2(wf0.w); pa += a06[3] * v + a04[3] * absv(v);
        v = cvt2(wl1.x) + cvt2(wr1.x) + cvt2(wf1.x); pb += a06[4] * v + a04[4] * absv(v);
        v = cvt2(wl1.y) + cvt2(wr1.y) + cvt2(wf1.y); pb += a06[5] * v + a04[5] * absv(v);
        v = cvt2(wl1.z) + cvt2(wr1.z) + cvt2(wf1.z); pb += a06[6] * v + a04[6] * absv(v);
        v = cvt2(wl1.w) + cvt2(wr1.w) + cvt2(wf1.w); pb += a06[7] * v + a04[7] * absv(v);
        float sa = pa.x + pa.y, sb = pb.x + pb.y;
        sa += __shfl_xor(sa, 1, 64);
        sb += __shfl_xor(sb, 1, 64);
        sa += __shfl_xor(sa, 2, 64);
        sb += __shfl_xor(sb, 2, 64);
        sa += __shfl_xor(sa, 4, 64);
        sb += __shfl_xor(sb, 4, 64);
        if ((ql & 7) == 0) {
            int hh = ql >> 3;                 // 0 or 1
            logit_s[e * 4 + hh] = sa;
            logit_s[e * 4 + 2 + hh] = sb;
        }
    }
    __syncthreads();
    if (tid < EB * 4) logits[(size_t)s0 * 4 + tid] = logit_s[tid];
}

// ---------------- node aggregation: WPN waves per node, 2-unrolled gather ----
template<int HC, int WPN, bool OUT_BF16>
__global__ __launch_bounds__(256) void node_agg_wave_kernel(
    const unsigned short* __restrict__ xl, int XS, const float* __restrict__ logits,
    const int* __restrict__ srcs, const int* __restrict__ offsets,
    const float* __restrict__ bias, void* __restrict__ outv) {
    constexpr int J = HC / (64 * WPN);    // 8 (L1) or 4 (L2)
    int tid = threadIdx.x;
    int wid = tid >> 6, lane = tid & 63;
    int n, ha;
    if constexpr (WPN == 2) { n = blockIdx.x * 2 + (wid >> 1); ha = wid & 1; }
    else { n = blockIdx.x * 4 + wid; ha = 0; }
    int o0 = offsets[n];
    int deg = offsets[n + 1] - o0;

    int hl;
    float m = -3.0e38f, s = 0.f;
    if constexpr (WPN == 2) {
        hl = ha * 2 + (lane >> 5);
        int p = lane & 31;
        for (int i = p; i < deg; i += 32)
            m = fmaxf(m, logits[(size_t)(o0 + i) * 4 + hl]);
        m = fmaxf(m, __shfl_xor(m, 1, 64));
        m = fmaxf(m, __shfl_xor(m, 2, 64));
        m = fmaxf(m, __shfl_xor(m, 4, 64));
        m = fmaxf(m, __shfl_xor(m, 8, 64));
        m = fmaxf(m, __shfl_xor(m, 16, 64));
        for (int i = p; i < deg; i += 32)
            s += __expf(logits[(size_t)(o0 + i) * 4 + hl] - m);
        s += __shfl_xor(s, 1, 64);
        s += __shfl_xor(s, 2, 64);
        s += __shfl_xor(s, 4, 64);
        s += __shfl_xor(s, 8, 64);
        s += __shfl_xor(s, 16, 64);
    } else {
        hl = lane >> 4;
        int p = lane & 15;
        for (int i = p; i < deg; i += 16)
            m = fmaxf(m, logits[(size_t)(o0 + i) * 4 + hl]);
        m = fmaxf(m, __shfl_xor(m, 1, 64));
        m = fmaxf(m, __shfl_xor(m, 2, 64));
        m = fmaxf(m, __shfl_xor(m, 4, 64));
        m = fmaxf(m, __shfl_xor(m, 8, 64));
        for (int i = p; i < deg; i += 16)
            s += __expf(logits[(size_t)(o0 + i) * 4 + hl] - m);
        s += __shfl_xor(s, 1, 64);
        s += __shfl_xor(s, 2, 64);
        s += __shfl_xor(s, 4, 64);
        s += __shfl_xor(s, 8, 64);
    }
    float inv = 1.f / (s + 1e-16f);

    int c0 = ha * (HC / WPN) + lane * J;
    float acc[J];
#pragma unroll
    for (int v = 0; v < J; v++) acc[v] = bias[c0 + v];

    int i = 0;
    for (; i + 2 <= deg; i += 2) {
        int sl0 = o0 + i, sl1 = o0 + i + 1;
        int src0 = srcs[sl0], src1 = srcs[sl1];
        const unsigned short* row0 = &xl[(size_t)src0 * XS + c0];
        const unsigned short* row1 = &xl[(size_t)src1 * XS + c0];
        float alpha0 = __expf(logits[(size_t)sl0 * 4 + hl] - m) * inv;
        float alpha1 = __expf(logits[(size_t)sl1 * 4 + hl] - m) * inv;
        if constexpr (J == 8) {
            u8x16 a0, a1;
            a0.v = *(const short8*)row0;
            a1.v = *(const short8*)row1;
#pragma unroll
            for (int v = 0; v < 8; v++) acc[v] += alpha0 * bits2f(a0.u[v]) + alpha1 * bits2f(a1.u[v]);
        } else {
            unsigned short u0[4], u1[4];
            *(ushort4*)u0 = *(const ushort4*)row0;
            *(ushort4*)u1 = *(const ushort4*)row1;
#pragma unroll
            for (int v = 0; v < 4; v++) acc[v] += alpha0 * bits2f(u0[v]) + alpha1 * bits2f(u1[v]);
        }
    }
    if (i < deg) {
        int sl = o0 + i;
        float alpha = __expf(logits[(size_t)sl * 4 + hl] - m) * inv;
        int src = srcs[sl];
        const unsigned short* row = &xl[(size_t)src * XS + c0];
        if constexpr (J == 8) {
            u8x16 a0; a0.v = *(const short8*)row;
#pragma unroll
            for (int v = 0; v < 8; v++) acc[v] += alpha * bits2f(a0.u[v]);
        } else {
            unsigned short us[4];
            *(ushort4*)us = *(const ushort4*)row;
#pragma unroll
            for (int v = 0; v < 4; v++) acc[v] += alpha * bits2f(us[v]);
        }
    }

    if constexpr (OUT_BF16) {
        unsigned short* o = (unsigned short*)outv;
        u8x16 w0;
#pragma unroll
        for (int v = 0; v < 8; v++) w0.u[v] = f2bits(fmaxf(acc[v], 0.f));
        *(short8*)&o[(size_t)n * HC + c0] = w0.v;
    } else {
        float* o = (float*)outv;
        float4 f;
        f.x = fmaxf(acc[0], 0.f); f.y = fmaxf(acc[1], 0.f);
        f.z = fmaxf(acc[2], 0.f); f.w = fmaxf(acc[3], 0.f);
        *(float4*)&o[(size_t)n * HC + c0] = f;
    }
}

// ---------------- MLP head ----------------
__global__ __launch_bounds__(64) void mlp_head_kernel(
    const float* __restrict__ h2, const int* __restrict__ nnod,
    const float* __restrict__ w1, const float* __restrict__ b1,
    const float* __restrict__ w2, const float* __restrict__ b2,
    float* __restrict__ out, int B) {
    int b = blockIdx.x, tid = threadIdx.x;
    int sum = 0;
    for (int j = tid; j <= b; j += 64) sum += nnod[j];
#pragma unroll
    for (int off = 32; off > 0; off >>= 1) sum += __shfl_xor(sum, off, 64);
    int node = sum - 1;
    __shared__ float mast[256];
    for (int i = tid; i < 256; i += 64) mast[i] = h2[(size_t)node * 256 + i];
    __syncthreads();
    float z = 0.f;
    for (int k = 0; k < 256; k++) z += mast[k] * w1[k * 64 + tid];
    z += b1[tid];
    z = z > 0.f ? z : 0.f;
    float p = z * w2[tid];
#pragma unroll
    for (int off = 32; off > 0; off >>= 1) p += __shfl_down(p, off, 64);
    if (tid == 0) out[b] = p + b2[0];
}

extern "C" void kernel_launch(void* const* d_in, const int* in_sizes, int n_in,
                              void* d_out, int out_size, void* d_ws, size_t ws_size,
                              hipStream_t stream) {
    const float* x     = (const float*)d_in[0];
    const int*   ei    = (const int*)d_in[1];
    const float* eattr = (const float*)d_in[2];
    const int*   nnod  = (const int*)d_in[3];
    const float* Wl1 = (const float*)d_in[4];
    const float* bl1 = (const float*)d_in[5];
    const float* Wr1 = (const float*)d_in[6];
    const float* br1 = (const float*)d_in[7];
    const float* We1 = (const float*)d_in[8];
    const float* att1= (const float*)d_in[9];
    const float* b1  = (const float*)d_in[10];
    const float* Wl2 = (const float*)d_in[11];
    const float* bl2 = (const float*)d_in[12];
    const float* Wr2 = (const float*)d_in[13];
    const float* br2 = (const float*)d_in[14];
    const float* We2 = (const float*)d_in[15];
    const float* att2= (const float*)d_in[16];
    const float* b2  = (const float*)d_in[17];
    const float* fc1w= (const float*)d_in[18];
    const float* fc1b= (const float*)d_in[19];
    const float* fc2w= (const float*)d_in[20];
    const float* fc2b= (const float*)d_in[21];
    float* out = (float*)d_out;

    const int N = NN, E = EE, B = BB;

    // ---------- workspace layout ----------
    char* base = (char*)d_ws;
    const size_t NB1 = (size_t)N * 1024 * 2;
    unsigned short* xl1   = (unsigned short*)base;
    unsigned short* xlxr2 = (unsigned short*)base;                       // [N][512]
    float*          h2    = (float*)(base + (size_t)N * 512 * 2);        // [N][256] f32
    unsigned short* xr1 = (unsigned short*)(base + NB1);
    unsigned short* h1  = (unsigned short*)(base + NB1);
    char* t = base + 2 * NB1;
    float* logits = (float*)t;        t += (size_t)E * 4 * sizeof(float);
    int* counts   = (int*)t;          t += (size_t)N * sizeof(int);
    int* offsets  = (int*)t;          t += (size_t)(N + 1) * sizeof(int);
    int* woff     = (int*)t;          t += (size_t)N * sizeof(int);
    int* perm     = (int*)t;          t += (size_t)E * sizeof(int);
    int* srcs     = (int*)t;          t += (size_t)E * sizeof(int);
    int* dsts     = (int*)t;          t += (size_t)E * sizeof(int);
    t = (char*)(((uintptr_t)t + 63) & ~(uintptr_t)63);
    unsigned short* xb    = (unsigned short*)t; t += (size_t)N * 128 * 2;
    unsigned short* wtl1  = (unsigned short*)t; t += (size_t)1024 * 128 * 2;   // contiguous with
    unsigned short* wtr1  = (unsigned short*)t; t += (size_t)1024 * 128 * 2;   //  wtl1 -> [2048][128]
    unsigned short* wtlr2 = (unsigned short*)t; t += (size_t)512 * 1024 * 2;
    unsigned short* weT1  = (unsigned short*)t; t += (size_t)1024 * 16 * 2;
    unsigned short* weT2  = (unsigned short*)t; t += (size_t)256 * 16 * 2;
    float* blr2           = (float*)t;          t += (size_t)512 * sizeof(float);
    size_t required = (size_t)(t - base);
    if (ws_size < required) return;   // guard: absmax-fail instead of abort

    dim3 blk(256);

    // ---------- CSR build ----------
    zero_int_kernel<<<(N + 255) / 256, blk, 0, stream>>>(counts, N);
    hist_kernel<<<(E + 255) / 256, blk, 0, stream>>>(ei, counts, E);
    scan_kernel<<<1, 1024, 0, stream>>>(counts, offsets, woff, N);
    scatter_kernel<<<(E + 255) / 256, blk, 0, stream>>>(ei, woff, perm, srcs, dsts, E);

    // ---------- conversions ----------
    convert_bf16_kernel<<<(N * 128 + 255) / 256, blk, 0, stream>>>(x, xb, N * 128);
    convert_weights_kernel<<<3154, blk, 0, stream>>>(Wl1, Wr1, Wl2, Wr2, We1, We2, bl2, br2,
                                                     wtl1, wtr1, wtlr2, weT1, weT2, blr2);

    // ---------- layer 1 (fused xl|xr GEMM, Ntot=2048, split write) ----------
    {
        dim3 g1(2048 / 128, N / 128);
        mfma_gemm_bt_kernel<<<g1, blk, 0, stream>>>(xb, wtl1, bl1, br1, xl1, xr1, N, 128, 1024);
    }
    edge_score_v10_kernel<1024><<<E / 8, blk, 0, stream>>>(xl1, xr1, 1024, eattr, weT1, att1, perm, srcs, dsts, logits, E);
    node_agg_wave_kernel<1024, 2, true><<<N / 2, blk, 0, stream>>>(xl1, 1024, logits, srcs, offsets, b1, h1);

    // ---------- layer 2 (fused xl|xr GEMM, N=512) ----------
    {
        dim3 g2(512 / 128, N / 128);
        mfma_gemm_bt_kernel<<<g2, blk, 0, stream>>>(h1, wtlr2, blr2, blr2, xlxr2, xlxr2, N, 1024, 512);
    }
    edge_score_v10_kernel<256><<<E / 16, blk, 0, stream>>>(xlxr2, xlxr2 + 256, 512, eattr, weT2, att2, perm, srcs, dsts, logits, E);
    node_agg_wave_kernel<256, 1, false><<<N / 4, blk, 0, stream>>>(xlxr2, 512, logits, srcs, offsets, b2, h2);

    // ---------- head ----------
    mlp_head_kernel<<<B, 64, 0, stream>>>(h2, nnod, fc1w, fc1b, fc2w, fc2b, out, B);
}

// Round 15
// 748.789 us; speedup vs baseline: 1.0889x; 1.0417x over previous
//
#include <hip/hip_runtime.h>
#include <hip/hip_bf16.h>
#include <cmath>

#define NN 49920
#define EE 200000
#define BB 128

typedef __attribute__((ext_vector_type(8))) short short8;
typedef __attribute__((ext_vector_type(4))) float floatx4;
typedef __attribute__((ext_vector_type(2))) float float2v;

union u8x16 { short8 v; unsigned short u[8]; };

__device__ __forceinline__ float bits2f(unsigned short u) {
    union { unsigned int i; float f; } c; c.i = ((unsigned int)u) << 16; return c.f;
}
__device__ __forceinline__ unsigned short f2bits(float f) {
    union { float f; unsigned int i; } c; c.f = f;
    unsigned int x = c.i;
    return (unsigned short)((x + 0x7fffu + ((x >> 16) & 1u)) >> 16);   // RNE
}
__device__ __forceinline__ unsigned short f2bits_trunc(float f) {
    union { float f; unsigned int i; } c; c.f = f;
    return (unsigned short)(c.i >> 16);                               // truncate (1 op)
}
__device__ __forceinline__ float2v cvt2(unsigned int w) {
    union { unsigned int i; float f; } lo, hi;
    lo.i = w << 16; hi.i = w & 0xffff0000u;
    return (float2v){lo.f, hi.f};
}
__device__ __forceinline__ float2v absv(float2v v) {
    union { float2v f; unsigned int u[2]; } c; c.f = v;
    c.u[0] &= 0x7fffffffu; c.u[1] &= 0x7fffffffu;
    return c.f;
}

typedef const __attribute__((address_space(1))) void* gvp;
typedef __attribute__((address_space(3))) void* lvp;
__device__ __forceinline__ void gll16(const void* g, void* l) {
    __builtin_amdgcn_global_load_lds((gvp)g, (lvp)l, 16, 0, 0);
}

// ---------------- small utility kernels ----------------
__global__ void zero_int_kernel(int* __restrict__ p, int n) {
    int i = blockIdx.x * blockDim.x + threadIdx.x;
    if (i < n) p[i] = 0;
}

__global__ void convert_bf16_kernel(const float* __restrict__ src, unsigned short* __restrict__ dst, int n) {
    int i = blockIdx.x * blockDim.x + threadIdx.x;
    if (i < n) dst[i] = f2bits(src[i]);
}

// fused conversion of ALL weights
__global__ void convert_weights_kernel(
    const float* __restrict__ Wl1, const float* __restrict__ Wr1,
    const float* __restrict__ Wl2, const float* __restrict__ Wr2,
    const float* __restrict__ We1, const float* __restrict__ We2,
    const float* __restrict__ bl2, const float* __restrict__ br2,
    unsigned short* __restrict__ wtl1, unsigned short* __restrict__ wtr1,
    unsigned short* __restrict__ wtlr2, unsigned short* __restrict__ weT1,
    unsigned short* __restrict__ weT2, float* __restrict__ blr2) {
    int b = blockIdx.x, tid = threadIdx.x;
    if (b < 1024) {                       // Wl1/Wr1 [128][1024] -> WT [1024][128]
        const float* W = (b < 512) ? Wl1 : Wr1;
        unsigned short* WT = (b < 512) ? wtl1 : wtr1;
        int i = ((b & 511) << 8) + tid;
        int n = i >> 7, k = i & 127;
        WT[i] = f2bits(W[k * 1024 + n]);
    } else if (b < 3072) {                // Wl2/Wr2 [1024][256] -> wtlr2 [512][1024]
        int bb = b - 1024;
        const float* W = (bb < 1024) ? Wl2 : Wr2;
        int i = ((bb & 1023) << 8) + tid;
        int n = i >> 10, k = i & 1023;
        int off = (bb < 1024) ? 0 : 262144;
        wtlr2[off + i] = f2bits(W[k * 256 + n]);
    } else if (b < 3136) {                // We1 [16][1024] -> weT1 [1024][16]
        int i = ((b - 3072) << 8) + tid;
        int col = i >> 4, k = i & 15;
        weT1[i] = f2bits(We1[k * 1024 + col]);
    } else if (b < 3152) {                // We2 [16][256] -> weT2 [256][16]
        int i = ((b - 3136) << 8) + tid;
        int col = i >> 4, k = i & 15;
        weT2[i] = f2bits(We2[k * 256 + col]);
    } else {                              // blr2 = bl2 | br2 (512 f32)
        int i = ((b - 3152) << 8) + tid;
        if (i < 512) blr2[i] = (i < 256) ? bl2[i] : br2[i - 256];
    }
}

// ---------------- bf16 MFMA GEMM (B^T input, async staging, split output) ----
__global__ __launch_bounds__(256) void mfma_gemm_bt_kernel(
    const unsigned short* __restrict__ A, const unsigned short* __restrict__ WT,
    const float* __restrict__ bias, const float* __restrict__ bias2,
    unsigned short* __restrict__ C, unsigned short* __restrict__ C2,
    int M, int K, int Nout) {
    __shared__ unsigned short As[128 * 32];
    __shared__ unsigned short Bs[128 * 32];
    int tid = threadIdx.x;
    int lane = tid & 63, wid = tid >> 6;
    int gm0 = blockIdx.y * 128, gn0 = blockIdx.x * 128;
    int wm = (wid & 1) * 64, wn = (wid >> 1) * 64;
    int l15 = lane & 15, quad = lane >> 4;
    int r0 = wid * 32;
    int gr = r0 + (lane >> 2);
    int kc = (lane & 3) * 8;

    floatx4 acc[4][4];
#pragma unroll
    for (int i = 0; i < 4; i++)
#pragma unroll
        for (int j = 0; j < 4; j++)
#pragma unroll
            for (int r = 0; r < 4; r++) acc[i][j][r] = 0.f;

    const unsigned short* Ap0 = &A[(size_t)(gm0 + gr) * K + kc];
    const unsigned short* Ap1 = Ap0 + (size_t)16 * K;
    const unsigned short* Bp0 = &WT[(size_t)(gn0 + gr) * K + kc];
    const unsigned short* Bp1 = Bp0 + (size_t)16 * K;
    unsigned short* as0 = &As[r0 * 32];
    unsigned short* as1 = &As[(r0 + 16) * 32];
    unsigned short* bs0 = &Bs[r0 * 32];
    unsigned short* bs1 = &Bs[(r0 + 16) * 32];

    for (int k0 = 0; k0 < K; k0 += 32) {
        __syncthreads();
        gll16(Ap0 + k0, as0);
        gll16(Ap1 + k0, as1);
        gll16(Bp0 + k0, bs0);
        gll16(Bp1 + k0, bs1);
        __syncthreads();
        short8 af[4], bfr[4];
#pragma unroll
        for (int i = 0; i < 4; i++)
            af[i] = *(const short8*)&As[(wm + 16 * i + l15) * 32 + quad * 8];
#pragma unroll
        for (int j = 0; j < 4; j++)
            bfr[j] = *(const short8*)&Bs[(wn + 16 * j + l15) * 32 + quad * 8];
#pragma unroll
        for (int i = 0; i < 4; i++)
#pragma unroll
            for (int j = 0; j < 4; j++)
                acc[i][j] = __builtin_amdgcn_mfma_f32_16x16x32_bf16(af[i], bfr[j], acc[i][j], 0, 0, 0);
    }

    unsigned short* Cw = C;
    const float* bp = bias;
    int colb = gn0 + wn + l15;
    if (gn0 >= Nout) { Cw = C2; bp = bias2; colb -= Nout; }
#pragma unroll
    for (int i = 0; i < 4; i++) {
#pragma unroll
        for (int j = 0; j < 4; j++) {
            int col = colb + 16 * j;
            float bv = bp[col];
#pragma unroll
            for (int r = 0; r < 4; r++) {
                int rrow = gm0 + wm + 16 * i + quad * 4 + r;
                Cw[(size_t)rrow * Nout + col] = f2bits(acc[i][j][r] + bv);
            }
        }
    }
}

// ---------------- CSR build ----------------
__global__ void hist_kernel(const int* __restrict__ ei, int* __restrict__ counts, int E) {
    int e = blockIdx.x * blockDim.x + threadIdx.x;
    if (e < E) atomicAdd(&counts[ei[E + e]], 1);
}

__global__ __launch_bounds__(1024) void scan_kernel(
    const int* __restrict__ counts, int* __restrict__ offsets,
    int* __restrict__ woff, int N) {
    __shared__ int partial[1024];
    int tid = threadIdx.x;
    const int CH = (N + 1023) >> 10;
    int b0 = tid * CH;
    int s = 0;
    for (int i = 0; i < CH; i++) { int idx = b0 + i; if (idx < N) s += counts[idx]; }
    partial[tid] = s;
    __syncthreads();
    if (tid == 0) {
        int acc = 0;
        for (int i = 0; i < 1024; i++) { int t = partial[i]; partial[i] = acc; acc += t; }
        offsets[N] = acc;
    }
    __syncthreads();
    int run = partial[tid];
    for (int i = 0; i < CH; i++) {
        int idx = b0 + i;
        if (idx < N) { offsets[idx] = run; woff[idx] = run; run += counts[idx]; }
    }
}

__global__ void scatter_kernel(const int* __restrict__ ei, int* __restrict__ woff,
                               int* __restrict__ perm, int* __restrict__ srcs,
                               int* __restrict__ dsts, int E) {
    int e = blockIdx.x * blockDim.x + threadIdx.x;
    if (e < E) {
        int d = ei[E + e];
        int slot = atomicAdd(&woff[d], 1);
        perm[slot] = e;
        srcs[slot] = ei[e];
        dsts[slot] = d;
    }
}

// ---------------- edge scoring v11 (= v8 layout, 0-conflict proven) ----------
// Half-wave (32 lanes) per edge; lane covers 8 ch via one uint4 (16B), 32
// lanes fully contiguous (512B) -> conflict-free b128 per round-12 evidence.
template<int HC>
__global__ __launch_bounds__(256) void edge_score_v11_kernel(
    const unsigned short* __restrict__ xl, const unsigned short* __restrict__ xr,
    int XS, const float* __restrict__ eattr, const unsigned short* __restrict__ WeT,
    const float* __restrict__ att, const int* __restrict__ perm,
    const int* __restrict__ srcs, const int* __restrict__ dsts,
    float* __restrict__ logits, int E) {
    constexpr int EB = (HC == 1024) ? 8 : 16;
    constexpr int LDE = HC + 8;
    __shared__ unsigned short ef_s[EB * LDE];
    __shared__ int src_s[EB], dst_s[EB], e_s[16];
    __shared__ float logit_s[EB * 4];

    int tid = threadIdx.x;
    int s0 = blockIdx.x * EB;
    int lane = tid & 63, w = tid >> 6;
    int l15 = lane & 15, quad = lane >> 4;

    if (tid < EB) { src_s[tid] = srcs[s0 + tid]; dst_s[tid] = dsts[s0 + tid]; }
    if (tid < 16) e_s[tid] = perm[s0 + (tid & (EB - 1))];
    __syncthreads();

    // A-frag: eattr rows (K zero-padded 16->32); trunc conversion (global only)
    u8x16 a;
    if (quad < 2) {
        const float* ap = &eattr[(size_t)e_s[l15] * 16 + quad * 8];
        float4 a0 = *(const float4*)ap;
        float4 a1 = *(const float4*)(ap + 4);
        a.u[0] = f2bits_trunc(a0.x); a.u[1] = f2bits_trunc(a0.y);
        a.u[2] = f2bits_trunc(a0.z); a.u[3] = f2bits_trunc(a0.w);
        a.u[4] = f2bits_trunc(a1.x); a.u[5] = f2bits_trunc(a1.y);
        a.u[6] = f2bits_trunc(a1.z); a.u[7] = f2bits_trunc(a1.w);
    } else {
#pragma unroll
        for (int j = 0; j < 8; j++) a.u[j] = 0;
    }

    // Phase 1: ef = eattr @ We -> LDS (bf16 trunc; rows >= EB discarded)
    for (int t = w; t < HC / 16; t += 4) {
        int col = t * 16 + l15;
        u8x16 b;
        if (quad < 2) *(uint4*)b.u = *(const uint4*)&WeT[(size_t)col * 16 + quad * 8];
        else {
#pragma unroll
            for (int j = 0; j < 8; j++) b.u[j] = 0;
        }
        floatx4 c = {0.f, 0.f, 0.f, 0.f};
        c = __builtin_amdgcn_mfma_f32_16x16x32_bf16(a.v, b.v, c, 0, 0, 0);
#pragma unroll
        for (int r = 0; r < 4; r++) {
            int row = quad * 4 + r;
            if (row < EB) ef_s[row * LDE + col] = f2bits_trunc(c[r]);
        }
    }
    __syncthreads();

    // Phase 2: 2 edges per wave (32-lane halves), lane covers 8 ch (uint4).
    int hf = lane >> 5, q = lane & 31;
    if constexpr (HC == 1024) {
        int c0 = w * 256 + q * 8;             // head w's channels
        float2v a06[4], a04[4];
#pragma unroll
        for (int j = 0; j < 4; j++) {
            float x0 = att[c0 + 2 * j], x1 = att[c0 + 2 * j + 1];
            a06[j] = (float2v){0.6f * x0, 0.6f * x1};
            a04[j] = (float2v){0.4f * x0, 0.4f * x1};
        }
        int prevd = -1;
        float2v r[4];
#pragma unroll
        for (int j = 0; j < 4; j++) r[j] = (float2v){0.f, 0.f};
#pragma unroll
        for (int pp = 0; pp < 4; pp++) {
            int e = pp * 2 + hf;
            int src = src_s[e], dst = dst_s[e];
            if (dst != prevd) {
                uint4 wr = *(const uint4*)&xr[(size_t)dst * XS + c0];
                r[0] = cvt2(wr.x); r[1] = cvt2(wr.y); r[2] = cvt2(wr.z); r[3] = cvt2(wr.w);
                prevd = dst;
            }
            uint4 wl = *(const uint4*)&xl[(size_t)src * XS + c0];
            uint4 wf = *(const uint4*)&ef_s[e * LDE + c0];
            float2v v, p2 = {0.f, 0.f};
            v = cvt2(wl.x) + r[0] + cvt2(wf.x); p2 += a06[0] * v + a04[0] * absv(v);
            v = cvt2(wl.y) + r[1] + cvt2(wf.y); p2 += a06[1] * v + a04[1] * absv(v);
            v = cvt2(wl.z) + r[2] + cvt2(wf.z); p2 += a06[2] * v + a04[2] * absv(v);
            v = cvt2(wl.w) + r[3] + cvt2(wf.w); p2 += a06[3] * v + a04[3] * absv(v);
            float part = p2.x + p2.y;
            part += __shfl_xor(part, 1, 64);
            part += __shfl_xor(part, 2, 64);
            part += __shfl_xor(part, 4, 64);
            part += __shfl_xor(part, 8, 64);
            part += __shfl_xor(part, 16, 64);
            if (q == 0) logit_s[e * 4 + w] = part;
        }
    } else {
        int c0 = q * 8;                       // all 256 ch over 32 lanes
        int hd = q >> 3;                      // lane's head
        float2v a06[4], a04[4];
#pragma unroll
        for (int j = 0; j < 4; j++) {
            float x0 = att[c0 + 2 * j], x1 = att[c0 + 2 * j + 1];
            a06[j] = (float2v){0.6f * x0, 0.6f * x1};
            a04[j] = (float2v){0.4f * x0, 0.4f * x1};
        }
        int prevd = -1;
        float2v r[4];
#pragma unroll
        for (int j = 0; j < 4; j++) r[j] = (float2v){0.f, 0.f};
#pragma unroll
        for (int pp = 0; pp < 2; pp++) {
            int e = w * 4 + pp * 2 + hf;
            int src = src_s[e], dst = dst_s[e];
            if (dst != prevd) {
                uint4 wr = *(const uint4*)&xr[(size_t)dst * XS + c0];
                r[0] = cvt2(wr.x); r[1] = cvt2(wr.y); r[2] = cvt2(wr.z); r[3] = cvt2(wr.w);
                prevd = dst;
            }
            uint4 wl = *(const uint4*)&xl[(size_t)src * XS + c0];
            uint4 wf = *(const uint4*)&ef_s[e * LDE + c0];
            float2v v, p2 = {0.f, 0.f};
            v = cvt2(wl.x) + r[0] + cvt2(wf.x); p2 += a06[0] * v + a04[0] * absv(v);
            v = cvt2(wl.y) + r[1] + cvt2(wf.y); p2 += a06[1] * v + a04[1] * absv(v);
            v = cvt2(wl.z) + r[2] + cvt2(wf.z); p2 += a06[2] * v + a04[2] * absv(v);
            v = cvt2(wl.w) + r[3] + cvt2(wf.w); p2 += a06[3] * v + a04[3] * absv(v);
            float part = p2.x + p2.y;
            part += __shfl_xor(part, 1, 64);
            part += __shfl_xor(part, 2, 64);
            part += __shfl_xor(part, 4, 64);
            if ((q & 7) == 0) logit_s[e * 4 + hd] = part;
        }
    }
    __syncthreads();
    if (tid < EB * 4) logits[(size_t)s0 * 4 + tid] = logit_s[tid];
}

// ---------------- node aggregation: WPN waves per node, 2-unrolled gather ----
template<int HC, int WPN, bool OUT_BF16>
__global__ __launch_bounds__(256) void node_agg_wave_kernel(
    const unsigned short* __restrict__ xl, int XS, const float* __restrict__ logits,
    const int* __restrict__ srcs, const int* __restrict__ offsets,
    const float* __restrict__ bias, void* __restrict__ outv) {
    constexpr int J = HC / (64 * WPN);    // 8 (L1) or 4 (L2)
    int tid = threadIdx.x;
    int wid = tid >> 6, lane = tid & 63;
    int n, ha;
    if constexpr (WPN == 2) { n = blockIdx.x * 2 + (wid >> 1); ha = wid & 1; }
    else { n = blockIdx.x * 4 + wid; ha = 0; }
    int o0 = offsets[n];
    int deg = offsets[n + 1] - o0;

    int hl;
    float m = -3.0e38f, s = 0.f;
    if constexpr (WPN == 2) {
        hl = ha * 2 + (lane >> 5);
        int p = lane & 31;
        for (int i = p; i < deg; i += 32)
            m = fmaxf(m, logits[(size_t)(o0 + i) * 4 + hl]);
        m = fmaxf(m, __shfl_xor(m, 1, 64));
        m = fmaxf(m, __shfl_xor(m, 2, 64));
        m = fmaxf(m, __shfl_xor(m, 4, 64));
        m = fmaxf(m, __shfl_xor(m, 8, 64));
        m = fmaxf(m, __shfl_xor(m, 16, 64));
        for (int i = p; i < deg; i += 32)
            s += __expf(logits[(size_t)(o0 + i) * 4 + hl] - m);
        s += __shfl_xor(s, 1, 64);
        s += __shfl_xor(s, 2, 64);
        s += __shfl_xor(s, 4, 64);
        s += __shfl_xor(s, 8, 64);
        s += __shfl_xor(s, 16, 64);
    } else {
        hl = lane >> 4;
        int p = lane & 15;
        for (int i = p; i < deg; i += 16)
            m = fmaxf(m, logits[(size_t)(o0 + i) * 4 + hl]);
        m = fmaxf(m, __shfl_xor(m, 1, 64));
        m = fmaxf(m, __shfl_xor(m, 2, 64));
        m = fmaxf(m, __shfl_xor(m, 4, 64));
        m = fmaxf(m, __shfl_xor(m, 8, 64));
        for (int i = p; i < deg; i += 16)
            s += __expf(logits[(size_t)(o0 + i) * 4 + hl] - m);
        s += __shfl_xor(s, 1, 64);
        s += __shfl_xor(s, 2, 64);
        s += __shfl_xor(s, 4, 64);
        s += __shfl_xor(s, 8, 64);
    }
    float inv = 1.f / (s + 1e-16f);

    int c0 = ha * (HC / WPN) + lane * J;
    float acc[J];
#pragma unroll
    for (int v = 0; v < J; v++) acc[v] = bias[c0 + v];

    int i = 0;
    for (; i + 2 <= deg; i += 2) {
        int sl0 = o0 + i, sl1 = o0 + i + 1;
        int src0 = srcs[sl0], src1 = srcs[sl1];
        const unsigned short* row0 = &xl[(size_t)src0 * XS + c0];
        const unsigned short* row1 = &xl[(size_t)src1 * XS + c0];
        float alpha0 = __expf(logits[(size_t)sl0 * 4 + hl] - m) * inv;
        float alpha1 = __expf(logits[(size_t)sl1 * 4 + hl] - m) * inv;
        if constexpr (J == 8) {
            u8x16 a0, a1;
            a0.v = *(const short8*)row0;
            a1.v = *(const short8*)row1;
#pragma unroll
            for (int v = 0; v < 8; v++) acc[v] += alpha0 * bits2f(a0.u[v]) + alpha1 * bits2f(a1.u[v]);
        } else {
            unsigned short u0[4], u1[4];
            *(ushort4*)u0 = *(const ushort4*)row0;
            *(ushort4*)u1 = *(const ushort4*)row1;
#pragma unroll
            for (int v = 0; v < 4; v++) acc[v] += alpha0 * bits2f(u0[v]) + alpha1 * bits2f(u1[v]);
        }
    }
    if (i < deg) {
        int sl = o0 + i;
        float alpha = __expf(logits[(size_t)sl * 4 + hl] - m) * inv;
        int src = srcs[sl];
        const unsigned short* row = &xl[(size_t)src * XS + c0];
        if constexpr (J == 8) {
            u8x16 a0; a0.v = *(const short8*)row;
#pragma unroll
            for (int v = 0; v < 8; v++) acc[v] += alpha * bits2f(a0.u[v]);
        } else {
            unsigned short us[4];
            *(ushort4*)us = *(const ushort4*)row;
#pragma unroll
            for (int v = 0; v < 4; v++) acc[v] += alpha * bits2f(us[v]);
        }
    }

    if constexpr (OUT_BF16) {
        unsigned short* o = (unsigned short*)outv;
        u8x16 w0;
#pragma unroll
        for (int v = 0; v < 8; v++) w0.u[v] = f2bits(fmaxf(acc[v], 0.f));
        *(short8*)&o[(size_t)n * HC + c0] = w0.v;
    } else {
        float* o = (float*)outv;
        float4 f;
        f.x = fmaxf(acc[0], 0.f); f.y = fmaxf(acc[1], 0.f);
        f.z = fmaxf(acc[2], 0.f); f.w = fmaxf(acc[3], 0.f);
        *(float4*)&o[(size_t)n * HC + c0] = f;
    }
}

// ---------------- MLP head ----------------
__global__ __launch_bounds__(64) void mlp_head_kernel(
    const float* __restrict__ h2, const int* __restrict__ nnod,
    const float* __restrict__ w1, const float* __restrict__ b1,
    const float* __restrict__ w2, const float* __restrict__ b2,
    float* __restrict__ out, int B) {
    int b = blockIdx.x, tid = threadIdx.x;
    int sum = 0;
    for (int j = tid; j <= b; j += 64) sum += nnod[j];
#pragma unroll
    for (int off = 32; off > 0; off >>= 1) sum += __shfl_xor(sum, off, 64);
    int node = sum - 1;
    __shared__ float mast[256];
    for (int i = tid; i < 256; i += 64) mast[i] = h2[(size_t)node * 256 + i];
    __syncthreads();
    float z = 0.f;
    for (int k = 0; k < 256; k++) z += mast[k] * w1[k * 64 + tid];
    z += b1[tid];
    z = z > 0.f ? z : 0.f;
    float p = z * w2[tid];
#pragma unroll
    for (int off = 32; off > 0; off >>= 1) p += __shfl_down(p, off, 64);
    if (tid == 0) out[b] = p + b2[0];
}

extern "C" void kernel_launch(void* const* d_in, const int* in_sizes, int n_in,
                              void* d_out, int out_size, void* d_ws, size_t ws_size,
                              hipStream_t stream) {
    const float* x     = (const float*)d_in[0];
    const int*   ei    = (const int*)d_in[1];
    const float* eattr = (const float*)d_in[2];
    const int*   nnod  = (const int*)d_in[3];
    const float* Wl1 = (const float*)d_in[4];
    const float* bl1 = (const float*)d_in[5];
    const float* Wr1 = (const float*)d_in[6];
    const float* br1 = (const float*)d_in[7];
    const float* We1 = (const float*)d_in[8];
    const float* att1= (const float*)d_in[9];
    const float* b1  = (const float*)d_in[10];
    const float* Wl2 = (const float*)d_in[11];
    const float* bl2 = (const float*)d_in[12];
    const float* Wr2 = (const float*)d_in[13];
    const float* br2 = (const float*)d_in[14];
    const float* We2 = (const float*)d_in[15];
    const float* att2= (const float*)d_in[16];
    const float* b2  = (const float*)d_in[17];
    const float* fc1w= (const float*)d_in[18];
    const float* fc1b= (const float*)d_in[19];
    const float* fc2w= (const float*)d_in[20];
    const float* fc2b= (const float*)d_in[21];
    float* out = (float*)d_out;

    const int N = NN, E = EE, B = BB;

    // ---------- workspace layout ----------
    char* base = (char*)d_ws;
    const size_t NB1 = (size_t)N * 1024 * 2;
    unsigned short* xl1   = (unsigned short*)base;
    unsigned short* xlxr2 = (unsigned short*)base;                       // [N][512]
    float*          h2    = (float*)(base + (size_t)N * 512 * 2);        // [N][256] f32
    unsigned short* xr1 = (unsigned short*)(base + NB1);
    unsigned short* h1  = (unsigned short*)(base + NB1);
    char* t = base + 2 * NB1;
    float* logits = (float*)t;        t += (size_t)E * 4 * sizeof(float);
    int* counts   = (int*)t;          t += (size_t)N * sizeof(int);
    int* offsets  = (int*)t;          t += (size_t)(N + 1) * sizeof(int);
    int* woff     = (int*)t;          t += (size_t)N * sizeof(int);
    int* perm     = (int*)t;          t += (size_t)E * sizeof(int);
    int* srcs     = (int*)t;          t += (size_t)E * sizeof(int);
    int* dsts     = (int*)t;          t += (size_t)E * sizeof(int);
    t = (char*)(((uintptr_t)t + 63) & ~(uintptr_t)63);
    unsigned short* xb    = (unsigned short*)t; t += (size_t)N * 128 * 2;
    unsigned short* wtl1  = (unsigned short*)t; t += (size_t)1024 * 128 * 2;   // contiguous with
    unsigned short* wtr1  = (unsigned short*)t; t += (size_t)1024 * 128 * 2;   //  wtl1 -> [2048][128]
    unsigned short* wtlr2 = (unsigned short*)t; t += (size_t)512 * 1024 * 2;
    unsigned short* weT1  = (unsigned short*)t; t += (size_t)1024 * 16 * 2;
    unsigned short* weT2  = (unsigned short*)t; t += (size_t)256 * 16 * 2;
    float* blr2           = (float*)t;          t += (size_t)512 * sizeof(float);
    size_t required = (size_t)(t - base);
    if (ws_size < required) return;   // guard: absmax-fail instead of abort

    dim3 blk(256);

    // ---------- CSR build ----------
    zero_int_kernel<<<(N + 255) / 256, blk, 0, stream>>>(counts, N);
    hist_kernel<<<(E + 255) / 256, blk, 0, stream>>>(ei, counts, E);
    scan_kernel<<<1, 1024, 0, stream>>>(counts, offsets, woff, N);
    scatter_kernel<<<(E + 255) / 256, blk, 0, stream>>>(ei, woff, perm, srcs, dsts, E);

    // ---------- conversions ----------
    convert_bf16_kernel<<<(N * 128 + 255) / 256, blk, 0, stream>>>(x, xb, N * 128);
    convert_weights_kernel<<<3154, blk, 0, stream>>>(Wl1, Wr1, Wl2, Wr2, We1, We2, bl2, br2,
                                                     wtl1, wtr1, wtlr2, weT1, weT2, blr2);

    // ---------- layer 1 (fused xl|xr GEMM, Ntot=2048, split write) ----------
    {
        dim3 g1(2048 / 128, N / 128);
        mfma_gemm_bt_kernel<<<g1, blk, 0, stream>>>(xb, wtl1, bl1, br1, xl1, xr1, N, 128, 1024);
    }
    edge_score_v11_kernel<1024><<<E / 8, blk, 0, stream>>>(xl1, xr1, 1024, eattr, weT1, att1, perm, srcs, dsts, logits, E);
    node_agg_wave_kernel<1024, 2, true><<<N / 2, blk, 0, stream>>>(xl1, 1024, logits, srcs, offsets, b1, h1);

    // ---------- layer 2 (fused xl|xr GEMM, N=512) ----------
    {
        dim3 g2(512 / 128, N / 128);
        mfma_gemm_bt_kernel<<<g2, blk, 0, stream>>>(h1, wtlr2, blr2, blr2, xlxr2, xlxr2, N, 1024, 512);
    }
    edge_score_v11_kernel<256><<<E / 16, blk, 0, stream>>>(xlxr2, xlxr2 + 256, 512, eattr, weT2, att2, perm, srcs, dsts, logits, E);
    node_agg_wave_kernel<256, 1, false><<<N / 4, blk, 0, stream>>>(xlxr2, 512, logits, srcs, offsets, b2, h2);

    // ---------- head ----------
    mlp_head_kernel<<<B, 64, 0, stream>>>(h2, nnod, fc1w, fc1b, fc2w, fc2b, out, B);
}